// Round 4
// baseline (376.173 us; speedup 1.0000x reference)
//
#include <hip/hip_runtime.h>

#define N_EDGES 1600000
#define N_NODES 50000
#define D_FEAT  32

// ---- workspace layout (bytes) ----
#define OFFS_BYTES   ((N_NODES + 1) * 4)
#define CURSOR_OFF   ((size_t)(((OFFS_BYTES + 255) / 256) * 256))
#define PERM_OFF     (CURSOR_OFF + (size_t)(((N_NODES * 4 + 255) / 256) * 256))
#define WS_NEEDED    (PERM_OFF + (size_t)N_EDGES * 4)

__global__ void zero_counts_kernel(int* __restrict__ cnt) {
    int i = blockIdx.x * blockDim.x + threadIdx.x;
    if (i <= N_NODES) cnt[i] = 0;
}

// Histogram: one edge per thread, non-returning atomics (fire-and-forget).
__global__ void hist_kernel(const int* __restrict__ index,
                            int* __restrict__ cnt) {
    int e = blockIdx.x * blockDim.x + threadIdx.x;
    if (e < N_EDGES) atomicAdd(&cnt[index[e]], 1);
}

// Single-block exclusive scan: counts -> offsets; also writes cursor = offsets.
__global__ __launch_bounds__(1024) void scan_offsets_kernel(int* __restrict__ cnt,
                                                            int* __restrict__ cursor) {
    const int T = 1024;
    const int C = (N_NODES + T - 1) / T;  // 49 per thread
    __shared__ int part[T];
    int t = threadIdx.x;
    int base = t * C;
    int s = 0;
    for (int j = 0; j < C; ++j) {
        int i = base + j;
        if (i < N_NODES) s += cnt[i];
    }
    part[t] = s;
    __syncthreads();
    int v = s;
    for (int d = 1; d < T; d <<= 1) {
        int w = (t >= d) ? part[t - d] : 0;
        __syncthreads();
        v += w;
        part[t] = v;
        __syncthreads();
    }
    int run = v - s;
    for (int j = 0; j < C; ++j) {
        int i = base + j;
        if (i < N_NODES) {
            int c = cnt[i];
            cnt[i] = run;
            cursor[i] = run;
            run += c;
        }
    }
    if (t == T - 1) cnt[N_NODES] = v;
}

// Fused rank+perm: one edge per thread -> one atomic + one dependent store.
// Max TLP: ~32 independent chains per wave, 6250 blocks cover all CUs.
__global__ void scatter_perm_kernel(const int* __restrict__ index,
                                    int* __restrict__ cursor,
                                    int* __restrict__ perm) {
    int e = blockIdx.x * blockDim.x + threadIdx.x;
    if (e >= N_EDGES) return;
    int pos = atomicAdd(&cursor[index[e]], 1);
    perm[pos] = e;
}

// One 64-lane wave per node. lane = slot*8 + f4: 8 edge-slots x 8 float4-lanes.
// 2-deep unroll -> up to 16 independent 128B row loads in flight per wave.
__global__ void gather_sum_kernel(const float4* __restrict__ src4,
                                  const int* __restrict__ perm,
                                  const int* __restrict__ offs,
                                  const float4* __restrict__ out_in4,
                                  float4* __restrict__ out4) {
    int wave = threadIdx.x >> 6;            // 4 waves / 256-thread block
    int node = blockIdx.x * 4 + wave;
    if (node >= N_NODES) return;
    int lane = threadIdx.x & 63;
    int slot = lane >> 3;                   // 0..7
    int f4   = lane & 7;                    // 0..7
    int start = offs[node];
    int end   = offs[node + 1];

    float4 a0 = {0.f, 0.f, 0.f, 0.f};
    float4 a1 = {0.f, 0.f, 0.f, 0.f};
    int i = start + slot;
    for (; i + 8 < end; i += 16) {
        int e0 = perm[i];
        int e1 = perm[i + 8];
        float4 v0 = src4[(size_t)e0 * 8 + f4];
        float4 v1 = src4[(size_t)e1 * 8 + f4];
        a0.x += v0.x; a0.y += v0.y; a0.z += v0.z; a0.w += v0.w;
        a1.x += v1.x; a1.y += v1.y; a1.z += v1.z; a1.w += v1.w;
    }
    if (i < end) {
        int e0 = perm[i];
        float4 v0 = src4[(size_t)e0 * 8 + f4];
        a0.x += v0.x; a0.y += v0.y; a0.z += v0.z; a0.w += v0.w;
    }
    a0.x += a1.x; a0.y += a1.y; a0.z += a1.z; a0.w += a1.w;

    for (int m = 8; m <= 32; m <<= 1) {
        a0.x += __shfl_xor(a0.x, m, 64);
        a0.y += __shfl_xor(a0.y, m, 64);
        a0.z += __shfl_xor(a0.z, m, 64);
        a0.w += __shfl_xor(a0.w, m, 64);
    }
    if (slot == 0) {
        size_t o = (size_t)node * 8 + f4;
        float4 b = out_in4[o];
        b.x += a0.x; b.y += a0.y; b.z += a0.z; b.w += a0.w;
        out4[o] = b;
    }
}

// ---- fallback (round-1 proven path) if ws is too small ----
__global__ void init_out_kernel(const float4* __restrict__ out_in,
                                float4* __restrict__ out, int n4) {
    int i = blockIdx.x * blockDim.x + threadIdx.x;
    int stride = gridDim.x * blockDim.x;
    for (; i < n4; i += stride) out[i] = out_in[i];
}
__global__ void scatter_add_kernel(const float4* __restrict__ src,
                                   const int* __restrict__ index,
                                   float* __restrict__ out) {
    const int total = N_EDGES * 8;
    int t = blockIdx.x * blockDim.x + threadIdx.x;
    int stride = gridDim.x * blockDim.x;
    for (; t < total; t += stride) {
        int e = t >> 3;
        int f = t & 7;
        float4 v = src[t];
        int node = index[e];
        float* o = out + (size_t)node * D_FEAT + f * 4;
        atomicAdd(o + 0, v.x);
        atomicAdd(o + 1, v.y);
        atomicAdd(o + 2, v.z);
        atomicAdd(o + 3, v.w);
    }
}

extern "C" void kernel_launch(void* const* d_in, const int* in_sizes, int n_in,
                              void* d_out, int out_size, void* d_ws, size_t ws_size,
                              hipStream_t stream) {
    const float* src    = (const float*)d_in[0];
    const int*   index  = (const int*)d_in[1];
    const float* out_in = (const float*)d_in[2];
    float* out          = (float*)d_out;

    if (ws_size < WS_NEEDED) {
        int n4 = out_size / 4;
        init_out_kernel<<<2048, 256, 0, stream>>>((const float4*)out_in, (float4*)out, n4);
        scatter_add_kernel<<<2048, 256, 0, stream>>>((const float4*)src, index, out);
        return;
    }

    char* ws = (char*)d_ws;
    int* offs   = (int*)ws;
    int* cursor = (int*)(ws + CURSOR_OFF);
    int* perm   = (int*)(ws + PERM_OFF);

    const int eb = (N_EDGES + 255) / 256;   // 6250 blocks, 1 thread/edge
    zero_counts_kernel<<<(N_NODES + 256) / 256, 256, 0, stream>>>(offs);
    hist_kernel<<<eb, 256, 0, stream>>>(index, offs);
    scan_offsets_kernel<<<1, 1024, 0, stream>>>(offs, cursor);
    scatter_perm_kernel<<<eb, 256, 0, stream>>>(index, cursor, perm);
    gather_sum_kernel<<<(N_NODES + 3) / 4, 256, 0, stream>>>(
        (const float4*)src, perm, offs, (const float4*)out_in, (float4*)out);
}

// Round 5
// 252.109 us; speedup vs baseline: 1.4921x; 1.4921x over previous
//
#include <hip/hip_runtime.h>

#define N_EDGES 1600000
#define N_NODES 50000
#define D_FEAT  32
#define SUB     16                       // sub-buckets per node (contention /16)
#define NB_BINS (N_NODES * SUB)          // 800000 bins
#define SCAN_BPB 4096                    // bins per scan block (1024 thr x int4)
#define SCAN_NBLK ((NB_BINS + SCAN_BPB - 1) / SCAN_BPB)  // 196

// ---- workspace layout (bytes) ----
#define OFFS_BYTES   ((NB_BINS + 1) * 4)
#define CURSOR_OFF   ((size_t)(((OFFS_BYTES + 255) / 256) * 256))
#define BSUM_OFF     (CURSOR_OFF + (size_t)(((NB_BINS * 4 + 255) / 256) * 256))
#define PERM_OFF     (BSUM_OFF + 1024)
#define WS_NEEDED    (PERM_OFF + (size_t)N_EDGES * 4)

__global__ void zero_bins_kernel(int4* __restrict__ cnt4) {
    int i = blockIdx.x * blockDim.x + threadIdx.x;
    int stride = gridDim.x * blockDim.x;
    const int n4 = NB_BINS / 4;
    for (; i < n4; i += stride) cnt4[i] = (int4){0, 0, 0, 0};
}

// Histogram into sub-bucketed bins: avg 2 edges/bin -> low same-address serialization.
__global__ void hist_kernel(const int* __restrict__ index,
                            int* __restrict__ cnt) {
    int e = blockIdx.x * blockDim.x + threadIdx.x;
    if (e < N_EDGES) atomicAdd(&cnt[index[e] * SUB + (e & (SUB - 1))], 1);
}

// Hierarchical scan kernel A: per-block sums of 4096 bins.
__global__ __launch_bounds__(1024) void scan_sums_kernel(const int4* __restrict__ cnt4,
                                                         int* __restrict__ bsum) {
    __shared__ int red[1024];
    int t = threadIdx.x;
    int i4 = blockIdx.x * 1024 + t;
    int s = 0;
    if (i4 < NB_BINS / 4) {
        int4 v = cnt4[i4];
        s = v.x + v.y + v.z + v.w;
    }
    red[t] = s;
    __syncthreads();
    for (int d = 512; d > 0; d >>= 1) {
        if (t < d) red[t] += red[t + d];
        __syncthreads();
    }
    if (t == 0) bsum[blockIdx.x] = red[0];
}

// Kernel B: exclusive scan of the 196 block sums (single block).
__global__ void scan_partials_kernel(int* __restrict__ bsum) {
    __shared__ int sh[256];
    int t = threadIdx.x;
    int v = (t < SCAN_NBLK) ? bsum[t] : 0;
    sh[t] = v;
    __syncthreads();
    int inc = v;
    for (int d = 1; d < 256; d <<= 1) {
        int w = (t >= d) ? sh[t - d] : 0;
        __syncthreads();
        inc += w;
        sh[t] = inc;
        __syncthreads();
    }
    if (t < SCAN_NBLK) bsum[t] = inc - v;   // exclusive
}

// Kernel C: local exclusive scan + block offset -> offs (in place) and cursor copy.
__global__ __launch_bounds__(1024) void scan_apply_kernel(int* __restrict__ cnt,
                                                          const int* __restrict__ bsum,
                                                          int* __restrict__ cursor) {
    __shared__ int part[1024];
    int t = threadIdx.x;
    int b = blockIdx.x;
    int i4 = b * 1024 + t;
    bool valid = i4 < NB_BINS / 4;
    int4 v = (int4){0, 0, 0, 0};
    if (valid) v = ((const int4*)cnt)[i4];
    int s = v.x + v.y + v.z + v.w;
    part[t] = s;
    __syncthreads();
    int inc = s;
    for (int d = 1; d < 1024; d <<= 1) {
        int w = (t >= d) ? part[t - d] : 0;
        __syncthreads();
        inc += w;
        part[t] = inc;
        __syncthreads();
    }
    int excl = inc - s + bsum[b];
    if (valid) {
        int4 o;
        o.x = excl;
        o.y = o.x + v.x;
        o.z = o.y + v.y;
        o.w = o.z + v.z;
        ((int4*)cnt)[i4] = o;
        ((int4*)cursor)[i4] = o;
    }
    if (b == 0 && t == 0) cnt[NB_BINS] = N_EDGES;  // total is statically known
}

// Fused rank+perm with /16 contention.
__global__ void scatter_perm_kernel(const int* __restrict__ index,
                                    int* __restrict__ cursor,
                                    int* __restrict__ perm) {
    int e = blockIdx.x * blockDim.x + threadIdx.x;
    if (e >= N_EDGES) return;
    int pos = atomicAdd(&cursor[index[e] * SUB + (e & (SUB - 1))], 1);
    perm[pos] = e;
}

// One wave per node; lane = slot*8 + f4. 4-deep unroll -> 32 independent
// 128B row loads in flight per wave.
__global__ void gather_sum_kernel(const float4* __restrict__ src4,
                                  const int* __restrict__ perm,
                                  const int* __restrict__ offs,
                                  const float4* __restrict__ out_in4,
                                  float4* __restrict__ out4) {
    int wave = threadIdx.x >> 6;
    int node = blockIdx.x * 4 + wave;
    if (node >= N_NODES) return;
    int lane = threadIdx.x & 63;
    int slot = lane >> 3;
    int f4   = lane & 7;
    int start = offs[node * SUB];
    int end   = offs[node * SUB + SUB];

    float4 a0 = {0,0,0,0}, a1 = {0,0,0,0}, a2 = {0,0,0,0}, a3 = {0,0,0,0};
    int i = start + slot;
    for (; i + 24 < end; i += 32) {
        int e0 = perm[i];
        int e1 = perm[i + 8];
        int e2 = perm[i + 16];
        int e3 = perm[i + 24];
        float4 v0 = src4[(size_t)e0 * 8 + f4];
        float4 v1 = src4[(size_t)e1 * 8 + f4];
        float4 v2 = src4[(size_t)e2 * 8 + f4];
        float4 v3 = src4[(size_t)e3 * 8 + f4];
        a0.x += v0.x; a0.y += v0.y; a0.z += v0.z; a0.w += v0.w;
        a1.x += v1.x; a1.y += v1.y; a1.z += v1.z; a1.w += v1.w;
        a2.x += v2.x; a2.y += v2.y; a2.z += v2.z; a2.w += v2.w;
        a3.x += v3.x; a3.y += v3.y; a3.z += v3.z; a3.w += v3.w;
    }
    for (; i < end; i += 8) {
        int e0 = perm[i];
        float4 v0 = src4[(size_t)e0 * 8 + f4];
        a0.x += v0.x; a0.y += v0.y; a0.z += v0.z; a0.w += v0.w;
    }
    a0.x += a1.x + a2.x + a3.x;
    a0.y += a1.y + a2.y + a3.y;
    a0.z += a1.z + a2.z + a3.z;
    a0.w += a1.w + a2.w + a3.w;

    for (int m = 8; m <= 32; m <<= 1) {
        a0.x += __shfl_xor(a0.x, m, 64);
        a0.y += __shfl_xor(a0.y, m, 64);
        a0.z += __shfl_xor(a0.z, m, 64);
        a0.w += __shfl_xor(a0.w, m, 64);
    }
    if (slot == 0) {
        size_t o = (size_t)node * 8 + f4;
        float4 b = out_in4[o];
        b.x += a0.x; b.y += a0.y; b.z += a0.z; b.w += a0.w;
        out4[o] = b;
    }
}

// ---- fallback (round-1 proven path) if ws is too small ----
__global__ void init_out_kernel(const float4* __restrict__ out_in,
                                float4* __restrict__ out, int n4) {
    int i = blockIdx.x * blockDim.x + threadIdx.x;
    int stride = gridDim.x * blockDim.x;
    for (; i < n4; i += stride) out[i] = out_in[i];
}
__global__ void scatter_add_kernel(const float4* __restrict__ src,
                                   const int* __restrict__ index,
                                   float* __restrict__ out) {
    const int total = N_EDGES * 8;
    int t = blockIdx.x * blockDim.x + threadIdx.x;
    int stride = gridDim.x * blockDim.x;
    for (; t < total; t += stride) {
        int e = t >> 3;
        int f = t & 7;
        float4 v = src[t];
        int node = index[e];
        float* o = out + (size_t)node * D_FEAT + f * 4;
        atomicAdd(o + 0, v.x);
        atomicAdd(o + 1, v.y);
        atomicAdd(o + 2, v.z);
        atomicAdd(o + 3, v.w);
    }
}

extern "C" void kernel_launch(void* const* d_in, const int* in_sizes, int n_in,
                              void* d_out, int out_size, void* d_ws, size_t ws_size,
                              hipStream_t stream) {
    const float* src    = (const float*)d_in[0];
    const int*   index  = (const int*)d_in[1];
    const float* out_in = (const float*)d_in[2];
    float* out          = (float*)d_out;

    if (ws_size < WS_NEEDED) {
        int n4 = out_size / 4;
        init_out_kernel<<<2048, 256, 0, stream>>>((const float4*)out_in, (float4*)out, n4);
        scatter_add_kernel<<<2048, 256, 0, stream>>>((const float4*)src, index, out);
        return;
    }

    char* ws = (char*)d_ws;
    int* offs   = (int*)ws;                 // bins -> offsets (in place)
    int* cursor = (int*)(ws + CURSOR_OFF);
    int* bsum   = (int*)(ws + BSUM_OFF);
    int* perm   = (int*)(ws + PERM_OFF);

    const int eb = (N_EDGES + 255) / 256;   // 6250 blocks, 1 thread/edge
    zero_bins_kernel<<<1024, 256, 0, stream>>>((int4*)offs);
    hist_kernel<<<eb, 256, 0, stream>>>(index, offs);
    scan_sums_kernel<<<SCAN_NBLK, 1024, 0, stream>>>((const int4*)offs, bsum);
    scan_partials_kernel<<<1, 256, 0, stream>>>(bsum);
    scan_apply_kernel<<<SCAN_NBLK, 1024, 0, stream>>>(offs, bsum, cursor);
    scatter_perm_kernel<<<eb, 256, 0, stream>>>(index, cursor, perm);
    gather_sum_kernel<<<(N_NODES + 3) / 4, 256, 0, stream>>>(
        (const float4*)src, perm, offs, (const float4*)out_in, (float4*)out);
}

// Round 6
// 227.486 us; speedup vs baseline: 1.6536x; 1.1082x over previous
//
#include <hip/hip_runtime.h>

#define N_EDGES 1600000
#define N_NODES 50000
#define D_FEAT  32

// ---- workspace layout (bytes) ----
// offs: int[N_NODES+1]; rank: int[N_EDGES]; perm: int[N_EDGES]
#define OFFS_BYTES   ((N_NODES + 1) * 4)
#define RANK_OFF     ((size_t)(((OFFS_BYTES + 255) / 256) * 256))
#define PERM_OFF     (RANK_OFF + (size_t)N_EDGES * 4)
#define WS_NEEDED    (PERM_OFF + (size_t)N_EDGES * 4)

__global__ void zero_counts_kernel(int* __restrict__ cnt) {
    int i = blockIdx.x * blockDim.x + threadIdx.x;
    if (i <= N_NODES) cnt[i] = 0;
}

// Returning atomic + COALESCED rank store (no dependent scattered store).
__global__ void hist_rank_kernel(const int* __restrict__ index,
                                 int* __restrict__ cnt,
                                 int* __restrict__ rank) {
    int e = blockIdx.x * blockDim.x + threadIdx.x;
    if (e < N_EDGES) rank[e] = atomicAdd(&cnt[index[e]], 1);
}

// Single-block in-place exclusive scan: counts -> offsets.
__global__ __launch_bounds__(1024) void scan_offsets_kernel(int* __restrict__ cnt) {
    const int T = 1024;
    const int C = (N_NODES + T - 1) / T;  // 49 per thread
    __shared__ int part[T];
    int t = threadIdx.x;
    int base = t * C;
    int s = 0;
    for (int j = 0; j < C; ++j) {
        int i = base + j;
        if (i < N_NODES) s += cnt[i];
    }
    part[t] = s;
    __syncthreads();
    int v = s;
    for (int d = 1; d < T; d <<= 1) {
        int w = (t >= d) ? part[t - d] : 0;
        __syncthreads();
        v += w;
        part[t] = v;
        __syncthreads();
    }
    int run = v - s;
    for (int j = 0; j < C; ++j) {
        int i = base + j;
        if (i < N_NODES) {
            int c = cnt[i];
            cnt[i] = run;
            run += c;
        }
    }
    if (t == T - 1) cnt[N_NODES] = v;
}

// Pure streaming pass: coalesced index+rank loads, cached offs gather,
// one independent scattered 4B store per thread (no atomic in the chain).
__global__ void build_perm_kernel(const int* __restrict__ index,
                                  const int* __restrict__ offs,
                                  const int* __restrict__ rank,
                                  int* __restrict__ perm) {
    int e = blockIdx.x * blockDim.x + threadIdx.x;
    if (e < N_EDGES) perm[offs[index[e]] + rank[e]] = e;
}

// One wave per node; lane = slot*8 + f4. 4-deep unroll -> 32 independent
// 128B row loads in flight per wave.
__global__ void gather_sum_kernel(const float4* __restrict__ src4,
                                  const int* __restrict__ perm,
                                  const int* __restrict__ offs,
                                  const float4* __restrict__ out_in4,
                                  float4* __restrict__ out4) {
    int wave = threadIdx.x >> 6;
    int node = blockIdx.x * 4 + wave;
    if (node >= N_NODES) return;
    int lane = threadIdx.x & 63;
    int slot = lane >> 3;
    int f4   = lane & 7;
    int start = offs[node];
    int end   = offs[node + 1];

    float4 a0 = {0,0,0,0}, a1 = {0,0,0,0}, a2 = {0,0,0,0}, a3 = {0,0,0,0};
    int i = start + slot;
    for (; i + 24 < end; i += 32) {
        int e0 = perm[i];
        int e1 = perm[i + 8];
        int e2 = perm[i + 16];
        int e3 = perm[i + 24];
        float4 v0 = src4[(size_t)e0 * 8 + f4];
        float4 v1 = src4[(size_t)e1 * 8 + f4];
        float4 v2 = src4[(size_t)e2 * 8 + f4];
        float4 v3 = src4[(size_t)e3 * 8 + f4];
        a0.x += v0.x; a0.y += v0.y; a0.z += v0.z; a0.w += v0.w;
        a1.x += v1.x; a1.y += v1.y; a1.z += v1.z; a1.w += v1.w;
        a2.x += v2.x; a2.y += v2.y; a2.z += v2.z; a2.w += v2.w;
        a3.x += v3.x; a3.y += v3.y; a3.z += v3.z; a3.w += v3.w;
    }
    for (; i < end; i += 8) {
        int e0 = perm[i];
        float4 v0 = src4[(size_t)e0 * 8 + f4];
        a0.x += v0.x; a0.y += v0.y; a0.z += v0.z; a0.w += v0.w;
    }
    a0.x += a1.x + a2.x + a3.x;
    a0.y += a1.y + a2.y + a3.y;
    a0.z += a1.z + a2.z + a3.z;
    a0.w += a1.w + a2.w + a3.w;

    for (int m = 8; m <= 32; m <<= 1) {
        a0.x += __shfl_xor(a0.x, m, 64);
        a0.y += __shfl_xor(a0.y, m, 64);
        a0.z += __shfl_xor(a0.z, m, 64);
        a0.w += __shfl_xor(a0.w, m, 64);
    }
    if (slot == 0) {
        size_t o = (size_t)node * 8 + f4;
        float4 b = out_in4[o];
        b.x += a0.x; b.y += a0.y; b.z += a0.z; b.w += a0.w;
        out4[o] = b;
    }
}

// ---- fallback (round-1 proven path) if ws is too small ----
__global__ void init_out_kernel(const float4* __restrict__ out_in,
                                float4* __restrict__ out, int n4) {
    int i = blockIdx.x * blockDim.x + threadIdx.x;
    int stride = gridDim.x * blockDim.x;
    for (; i < n4; i += stride) out[i] = out_in[i];
}
__global__ void scatter_add_kernel(const float4* __restrict__ src,
                                   const int* __restrict__ index,
                                   float* __restrict__ out) {
    const int total = N_EDGES * 8;
    int t = blockIdx.x * blockDim.x + threadIdx.x;
    int stride = gridDim.x * blockDim.x;
    for (; t < total; t += stride) {
        int e = t >> 3;
        int f = t & 7;
        float4 v = src[t];
        int node = index[e];
        float* o = out + (size_t)node * D_FEAT + f * 4;
        atomicAdd(o + 0, v.x);
        atomicAdd(o + 1, v.y);
        atomicAdd(o + 2, v.z);
        atomicAdd(o + 3, v.w);
    }
}

extern "C" void kernel_launch(void* const* d_in, const int* in_sizes, int n_in,
                              void* d_out, int out_size, void* d_ws, size_t ws_size,
                              hipStream_t stream) {
    const float* src    = (const float*)d_in[0];
    const int*   index  = (const int*)d_in[1];
    const float* out_in = (const float*)d_in[2];
    float* out          = (float*)d_out;

    if (ws_size < WS_NEEDED) {
        int n4 = out_size / 4;
        init_out_kernel<<<2048, 256, 0, stream>>>((const float4*)out_in, (float4*)out, n4);
        scatter_add_kernel<<<2048, 256, 0, stream>>>((const float4*)src, index, out);
        return;
    }

    char* ws = (char*)d_ws;
    int* offs = (int*)ws;
    int* rank = (int*)(ws + RANK_OFF);
    int* perm = (int*)(ws + PERM_OFF);

    const int eb = (N_EDGES + 255) / 256;   // 6250 blocks, 1 thread/edge
    zero_counts_kernel<<<(N_NODES + 256) / 256, 256, 0, stream>>>(offs);
    hist_rank_kernel<<<eb, 256, 0, stream>>>(index, offs, rank);
    scan_offsets_kernel<<<1, 1024, 0, stream>>>(offs);
    build_perm_kernel<<<eb, 256, 0, stream>>>(index, offs, rank, perm);
    gather_sum_kernel<<<(N_NODES + 3) / 4, 256, 0, stream>>>(
        (const float4*)src, perm, offs, (const float4*)out_in, (float4*)out);
}